// Round 9
// baseline (3014.944 us; speedup 1.0000x reference)
//
#include <hip/hip_runtime.h>

#define M_TOTAL 65536   // B*T rows
#define DDIM    128     // latent dim (GEMM K)
#define KCODES  1024    // codebook size (GEMM N)
#define NQ      8       // RVQ stages
#define RROWS   64      // rows per block (4 waves in 2x2 row/code grid)
#define NC      64      // codes per Es chunk
#define NCHUNKS (KCODES / NC)
#define TAU     0.15f   // margin threshold (validated rounds 5-8, absmax 0)

typedef _Float16 half8 __attribute__((ext_vector_type(8)));
typedef float    f32x4 __attribute__((ext_vector_type(4)));

// ---------------- ||e||^2 (verified round-1 semantics) ----------------
__global__ __launch_bounds__(256) void enorm_kernel(const float* __restrict__ embed,
                                                    float* __restrict__ enorm) {
  int c = blockIdx.x * 4 + (threadIdx.x >> 6);
  int lane = threadIdx.x & 63;
  const float* e = embed + (size_t)c * DDIM;
  float v0 = e[lane];
  float v1 = e[lane + 64];
  float s = fmaf(v0, v0, v1 * v1);
  #pragma unroll
  for (int off = 32; off > 0; off >>= 1) s += __shfl_down(s, off);
  if (lane == 0) enorm[c] = s;
}

// ---------------- embed -> f16 plane, row-major ----------------
__global__ __launch_bounds__(256) void esplit16_kernel(const float* __restrict__ embed,
                                                       _Float16* __restrict__ Ef16) {
  size_t base = ((size_t)blockIdx.x * 256 + threadIdx.x) * 8;
  float4 v0 = *(const float4*)(embed + base);
  float4 v1 = *(const float4*)(embed + base + 4);
  half8 h;
  h[0] = (_Float16)v0.x; h[1] = (_Float16)v0.y; h[2] = (_Float16)v0.z; h[3] = (_Float16)v0.w;
  h[4] = (_Float16)v1.x; h[5] = (_Float16)v1.y; h[6] = (_Float16)v1.z; h[7] = (_Float16)v1.w;
  *(half8*)(Ef16 + base) = h;
}

// ---------------- one RVQ stage: dbuf f16 MFMA screen + in-block exact fixup ----
// Block: 64 rows x 1024 codes (16 chunks of 64). 4 waves 2x2: rw=wv&1 -> rows
// rw*32 + rt*16 + l15; cw=wv>>1 -> codes cw*32 + ct*16 + l15 within a chunk.
// Es double-buffered (1 barrier/chunk); grid 1024 blocks -> 4 blocks/CU so
// barrier drains overlap across blocks. Top-2 margin; rows with margin <= TAU
// get an exact fp32 in-block recheck (round-1-verified fmaf-chain semantics).
__global__ __launch_bounds__(256, 4) void rvq_stage(
    const float* __restrict__ rin, float* __restrict__ rout,
    const _Float16* __restrict__ Ef16S,     // [KCODES][DDIM] f16, this stage
    const float* __restrict__ embedS,       // [KCODES][DDIM] fp32, this stage
    const float* __restrict__ enormS,       // [KCODES]
    int* __restrict__ codesS,               // [M_TOTAL] this stage
    int write_resid)
{
  __shared__ _Float16 Es[2][NC * 136];      // 2 x 17408 B
  __shared__ int nflag;
  // overlays on Es after the main loop (Es dead then; barriers order reuse):
  float* redv1  = (float*)Es;               // [64][2]
  float* redv2  = redv1 + 128;              // [64][2]
  int*   redi1  = (int*)(redv2 + 128);      // [64][2]
  int*   bcode  = redi1 + 128;              // [64]
  int*   flagged= bcode + 64;               // [64]
  float* rowbuf = (float*)(flagged + 64);   // [128]
  float* fv     = rowbuf + 128;             // [256]
  int*   fidx   = (int*)(fv + 256);         // [256]

  const int tid = threadIdx.x;
  const int wv = tid >> 6;
  const int l  = tid & 63;
  const int l15 = l & 15;
  const int q = l >> 4;
  const int rw = wv & 1;
  const int cw = wv >> 1;
  const int row_base = blockIdx.x * RROWS;

  if (tid == 0) nflag = 0;

  // staging indices (64 codes x 128 k per chunk; 4 half8 per thread, coalesced)
  const int s_code = tid >> 4;              // 0..15 (+16 per it)
  const int s_kp   = tid & 15;

  // ---- build f16 A-frags from global (once): af[rt][kc], A[m=l15][k=q*8+j] ----
  half8 af[2][4];
  #pragma unroll
  for (int rt = 0; rt < 2; ++rt) {
    const float* pa = rin + (size_t)(row_base + rw * 32 + rt * 16 + l15) * DDIM;
    #pragma unroll
    for (int kc = 0; kc < 4; ++kc) {
      float4 x0 = *(const float4*)(pa + kc * 32 + q * 8);
      float4 x1 = *(const float4*)(pa + kc * 32 + q * 8 + 4);
      half8 h;
      h[0] = (_Float16)x0.x; h[1] = (_Float16)x0.y; h[2] = (_Float16)x0.z; h[3] = (_Float16)x0.w;
      h[4] = (_Float16)x1.x; h[5] = (_Float16)x1.y; h[6] = (_Float16)x1.z; h[7] = (_Float16)x1.w;
      af[rt][kc] = h;
    }
  }

  // ---- prologue: stage chunk 0 into Es[0] ----
  half8 pre[4];
  #pragma unroll
  for (int it = 0; it < 4; ++it)
    pre[it] = *(const half8*)(Ef16S + (size_t)(it * 16 + s_code) * DDIM + s_kp * 8);
  #pragma unroll
  for (int it = 0; it < 4; ++it)
    *(half8*)(&Es[0][(it * 16 + s_code) * 136 + s_kp * 8]) = pre[it];
  __syncthreads();

  float v1[8], v2[8];
  int i1[8];
  #pragma unroll
  for (int s = 0; s < 8; ++s) { v1[s] = -3.0e38f; v2[s] = -3.0e38f; i1[s] = 0x7fffffff; }

  for (int cc = 0; cc < NCHUNKS; ++cc) {
    const int cur = cc & 1;

    // issue global loads for chunk cc+1 (latency hides behind this chunk's compute)
    if (cc + 1 < NCHUNKS) {
      #pragma unroll
      for (int it = 0; it < 4; ++it)
        pre[it] = *(const half8*)(Ef16S + (size_t)((cc + 1) * NC + it * 16 + s_code) * DDIM + s_kp * 8);
    }
    float enr0 = enormS[cc * NC + cw * 32 + l15];
    float enr1 = enormS[cc * NC + cw * 32 + 16 + l15];

    f32x4 acc[2][2];
    #pragma unroll
    for (int rt = 0; rt < 2; ++rt)
      #pragma unroll
      for (int ct = 0; ct < 2; ++ct) acc[rt][ct] = (f32x4){0.f, 0.f, 0.f, 0.f};

    #pragma unroll
    for (int kc = 0; kc < 4; ++kc) {
      half8 bf0 = *(const half8*)(&Es[cur][(cw * 32 + l15) * 136 + kc * 32 + q * 8]);
      half8 bf1 = *(const half8*)(&Es[cur][(cw * 32 + 16 + l15) * 136 + kc * 32 + q * 8]);
      #pragma unroll
      for (int rt = 0; rt < 2; ++rt) {
        acc[rt][0] = __builtin_amdgcn_mfma_f32_16x16x32_f16(af[rt][kc], bf0, acc[rt][0], 0, 0, 0);
        acc[rt][1] = __builtin_amdgcn_mfma_f32_16x16x32_f16(af[rt][kc], bf1, acc[rt][1], 0, 0, 0);
      }
    }

    // epilogue: dist = 2*dot - ||e||^2; branchless top-2 (inline, NO lambda --
    // round-8 lambda caused scratch spill). Codes ascend -> strict > keeps
    // first occurrence; exact ties -> margin 0 <= TAU -> exact fixup decides.
    #pragma unroll
    for (int ct = 0; ct < 2; ++ct) {
      float en = ct ? enr1 : enr0;
      int cgi = cc * NC + cw * 32 + ct * 16 + l15;
      #pragma unroll
      for (int rt = 0; rt < 2; ++rt)
        #pragma unroll
        for (int reg = 0; reg < 4; ++reg) {
          float d = fmaf(2.0f, acc[rt][ct][reg], -en);
          int s = rt * 4 + reg;
          v2[s] = fmaxf(v2[s], fminf(d, v1[s]));
          if (d > v1[s]) i1[s] = cgi;
          v1[s] = fmaxf(v1[s], d);
        }
    }

    // write prefetched chunk into the other buffer; one barrier per chunk
    if (cc + 1 < NCHUNKS) {
      #pragma unroll
      for (int it = 0; it < 4; ++it)
        *(half8*)(&Es[cur ^ 1][(it * 16 + s_code) * 136 + s_kp * 8]) = pre[it];
    }
    __syncthreads();
  }

  // ---- merge top-2 across the 16 l15-lanes sharing each row (disjoint codes) ----
  #pragma unroll
  for (int s = 0; s < 8; ++s) {
    #pragma unroll
    for (int off = 1; off < 16; off <<= 1) {
      float ov1 = __shfl_xor(v1[s], off);
      int   oi1 = __shfl_xor(i1[s], off);
      float ov2 = __shfl_xor(v2[s], off);
      if (ov1 > v1[s] || (ov1 == v1[s] && oi1 < i1[s])) {
        float nv2 = fmaxf(v1[s], ov2);
        v1[s] = ov1; i1[s] = oi1; v2[s] = nv2;
      } else {
        v2[s] = fmaxf(v2[s], ov1);
      }
    }
  }
  if (l15 == 0) {
    #pragma unroll
    for (int s = 0; s < 8; ++s) {
      int row = rw * 32 + (s >> 2) * 16 + q * 4 + (s & 3);
      redv1[row * 2 + cw] = v1[s];
      redi1[row * 2 + cw] = i1[s];
      redv2[row * 2 + cw] = v2[s];
    }
  }
  __syncthreads();

  // ---- final per-row merge (2 code-groups), flag, best code ----
  if (tid < RROWS) {
    float a1 = redv1[tid * 2], a2 = redv2[tid * 2];
    int ai = redi1[tid * 2];
    float b1v = redv1[tid * 2 + 1], b2v = redv2[tid * 2 + 1];
    int bi = redi1[tid * 2 + 1];
    float bv1, bv2; int bidx;
    if (b1v > a1 || (b1v == a1 && bi < ai)) {
      bv1 = b1v; bidx = bi; bv2 = fmaxf(a1, b2v);
    } else {
      bv1 = a1; bidx = ai; bv2 = fmaxf(b1v, a2);
    }
    bcode[tid] = bidx;
    if (bv1 - bv2 <= TAU) {
      int pos = atomicAdd(&nflag, 1);
      flagged[pos] = tid;
    }
  }
  __syncthreads();

  // ---- in-block exact fixup for flagged rows (round-1-verified fp32 semantics;
  //      rin IS the exact f32 residual for this stage) ----
  const int nfl = nflag;
  for (int f = 0; f < nfl; ++f) {
    const int r = flagged[f];
    if (tid < 32)
      *(float4*)(rowbuf + tid * 4) =
          *(const float4*)(rin + (size_t)(row_base + r) * DDIM + tid * 4);
    __syncthreads();

    float acc0 = 0.f, acc1 = 0.f, acc2 = 0.f, acc3 = 0.f;
    for (int k4 = 0; k4 < 32; ++k4) {
      float4 rb = *(const float4*)(&rowbuf[k4 * 4]);
      const float* eb = embedS + (size_t)tid * 4 * DDIM + k4 * 4;
      float4 e0 = *(const float4*)eb;
      float4 e1 = *(const float4*)(eb + DDIM);
      float4 e2 = *(const float4*)(eb + 2 * DDIM);
      float4 e3 = *(const float4*)(eb + 3 * DDIM);
      acc0 = fmaf(rb.x, e0.x, acc0); acc0 = fmaf(rb.y, e0.y, acc0);
      acc0 = fmaf(rb.z, e0.z, acc0); acc0 = fmaf(rb.w, e0.w, acc0);
      acc1 = fmaf(rb.x, e1.x, acc1); acc1 = fmaf(rb.y, e1.y, acc1);
      acc1 = fmaf(rb.z, e1.z, acc1); acc1 = fmaf(rb.w, e1.w, acc1);
      acc2 = fmaf(rb.x, e2.x, acc2); acc2 = fmaf(rb.y, e2.y, acc2);
      acc2 = fmaf(rb.z, e2.z, acc2); acc2 = fmaf(rb.w, e2.w, acc2);
      acc3 = fmaf(rb.x, e3.x, acc3); acc3 = fmaf(rb.y, e3.y, acc3);
      acc3 = fmaf(rb.z, e3.z, acc3); acc3 = fmaf(rb.w, e3.w, acc3);
    }
    float bv = -3.0e38f; int bi = 0x7fffffff;
    {
      float dd0 = 2.0f * acc0 - enormS[tid * 4 + 0];
      float dd1 = 2.0f * acc1 - enormS[tid * 4 + 1];
      float dd2 = 2.0f * acc2 - enormS[tid * 4 + 2];
      float dd3 = 2.0f * acc3 - enormS[tid * 4 + 3];
      bv = dd0; bi = tid * 4 + 0;
      if (dd1 > bv) { bv = dd1; bi = tid * 4 + 1; }
      if (dd2 > bv) { bv = dd2; bi = tid * 4 + 2; }
      if (dd3 > bv) { bv = dd3; bi = tid * 4 + 3; }
    }
    fv[tid] = bv; fidx[tid] = bi;
    __syncthreads();
    for (int step = 128; step > 0; step >>= 1) {
      if (tid < step) {
        float o = fv[tid + step]; int oi = fidx[tid + step];
        if (o > fv[tid] || (o == fv[tid] && oi < fidx[tid])) { fv[tid] = o; fidx[tid] = oi; }
      }
      __syncthreads();
    }
    if (tid == 0) bcode[r] = fidx[0];
    __syncthreads();
  }

  // ---- write codes; exact f32 residual update (block owns its rows) ----
  if (tid < RROWS) codesS[row_base + tid] = bcode[tid];
  __syncthreads();

  if (write_resid) {
    #pragma unroll
    for (int it = 0; it < 8; ++it) {
      int idx = it * 256 + tid;
      int r = idx >> 5, f4 = idx & 31;
      float4 e = *(const float4*)(embedS + (size_t)bcode[r] * DDIM + f4 * 4);
      float4 a = *(const float4*)(rin + (size_t)(row_base + r) * DDIM + f4 * 4);
      float4 o;
      o.x = a.x - e.x; o.y = a.y - e.y; o.z = a.z - e.z; o.w = a.w - e.w;
      *(float4*)(rout + (size_t)(row_base + r) * DDIM + f4 * 4) = o;
    }
  }
}

// ================= fallback: round-2 verified exact-fp32 kernel =================
#define F_NCHUNK  256
#define F_KC      16
#define F_AS_STRIDE 68
#define F_ES_STRIDE 260

__global__ __launch_bounds__(256, 3) void rvq_stage_kernel(
    const float* __restrict__ rin, float* __restrict__ rout,
    const float* __restrict__ embed, const float* __restrict__ enorm,
    int* __restrict__ codes)
{
  __shared__ float smem[DDIM * F_AS_STRIDE + F_KC * F_ES_STRIDE + F_NCHUNK];
  float* As  = smem;
  float* Es  = smem + DDIM * F_AS_STRIDE;
  float* Ens = Es + F_KC * F_ES_STRIDE;
  float* red_v = Es;
  int*   red_i = (int*)(Es + 64 * 33);
  int*   bcode = (int*)(Es + 2 * 64 * 33);

  const int tid = threadIdx.x;
  const int tx = tid & 31;
  const int ty = tid >> 5;
  const int row_base = blockIdx.x * 64;

  #pragma unroll
  for (int it = 0; it < 8; ++it) {
    int idx = it * 256 + tid;
    int r = idx >> 5, f4 = idx & 31;
    float4 v = *(const float4*)(rin + (size_t)(row_base + r) * DDIM + f4 * 4);
    As[(4 * f4 + 0) * F_AS_STRIDE + r] = v.x;
    As[(4 * f4 + 1) * F_AS_STRIDE + r] = v.y;
    As[(4 * f4 + 2) * F_AS_STRIDE + r] = v.z;
    As[(4 * f4 + 3) * F_AS_STRIDE + r] = v.w;
  }

  float best[8]; int bidx[8];
  #pragma unroll
  for (int i = 0; i < 8; ++i) { best[i] = -3.0e38f; bidx[i] = 0x7fffffff; }

  for (int nc = 0; nc < KCODES / F_NCHUNK; ++nc) {
    float acc[8][8];
    #pragma unroll
    for (int i = 0; i < 8; ++i)
      #pragma unroll
      for (int j = 0; j < 8; ++j) acc[i][j] = 0.0f;

    for (int kc = 0; kc < DDIM / F_KC; ++kc) {
      __syncthreads();
      #pragma unroll
      for (int it = 0; it < 4; ++it) {
        int idx = it * 256 + tid;
        int c = idx >> 2, f4 = idx & 3;
        float4 v = *(const float4*)(embed + (size_t)(nc * F_NCHUNK + c) * DDIM + kc * F_KC + f4 * 4);
        Es[(4 * f4 + 0) * F_ES_STRIDE + c] = v.x;
        Es[(4 * f4 + 1) * F_ES_STRIDE + c] = v.y;
        Es[(4 * f4 + 2) * F_ES_STRIDE + c] = v.z;
        Es[(4 * f4 + 3) * F_ES_STRIDE + c] = v.w;
      }
      if (kc == 0) Ens[tid] = enorm[nc * F_NCHUNK + tid];
      __syncthreads();

      const float* pa = As + kc * F_KC * F_AS_STRIDE + ty * 8;
      const float* pe = Es + 4 * tx;
      #pragma unroll 4
      for (int k = 0; k < F_KC; ++k) {
        float4 a0 = *(const float4*)(pa + k * F_AS_STRIDE);
        float4 a1 = *(const float4*)(pa + k * F_AS_STRIDE + 4);
        float4 e0 = *(const float4*)(pe + k * F_ES_STRIDE);
        float4 e1 = *(const float4*)(pe + k * F_ES_STRIDE + 128);
        float aa[8] = {a0.x, a0.y, a0.z, a0.w, a1.x, a1.y, a1.z, a1.w};
        float ee[8] = {e0.x, e0.y, e0.z, e0.w, e1.x, e1.y, e1.z, e1.w};
        #pragma unroll
        for (int i = 0; i < 8; ++i)
          #pragma unroll
          for (int j = 0; j < 8; ++j)
            acc[i][j] = fmaf(aa[i], ee[j], acc[i][j]);
      }
    }

    #pragma unroll
    for (int j = 0; j < 8; ++j) {
      int c_local = (j < 4) ? (4 * tx + j) : (128 + 4 * tx + (j - 4));
      float en = Ens[c_local];
      int cg = nc * F_NCHUNK + c_local;
      #pragma unroll
      for (int i = 0; i < 8; ++i) {
        float dist = 2.0f * acc[i][j] - en;
        if (dist > best[i] || (dist == best[i] && cg < bidx[i])) { best[i] = dist; bidx[i] = cg; }
      }
    }
  }

  __syncthreads();
  #pragma unroll
  for (int i = 0; i < 8; ++i) {
    red_v[(ty * 8 + i) * 33 + tx] = best[i];
    red_i[(ty * 8 + i) * 33 + tx] = bidx[i];
  }
  __syncthreads();
  if (tid < 64) {
    float bv = red_v[tid * 33]; int bi = red_i[tid * 33];
    #pragma unroll
    for (int t = 1; t < 32; ++t) {
      float v = red_v[tid * 33 + t]; int ix = red_i[tid * 33 + t];
      if (v > bv || (v == bv && ix < bi)) { bv = v; bi = ix; }
    }
    codes[row_base + tid] = bi;
    bcode[tid] = bi;
  }
  __syncthreads();
  #pragma unroll
  for (int it = 0; it < 32; ++it) {
    int idx = it * 256 + tid;
    int r = idx >> 7, d = idx & 127;
    float e = embed[(size_t)bcode[r] * DDIM + d];
    rout[(size_t)(row_base + r) * DDIM + d] = As[d * F_AS_STRIDE + r] - e;
  }
}

extern "C" void kernel_launch(void* const* d_in, const int* in_sizes, int n_in,
                              void* d_out, int out_size, void* d_ws, size_t ws_size,
                              hipStream_t stream) {
  (void)in_sizes; (void)n_in; (void)out_size;
  const float* x = (const float*)d_in[0];
  const float* embed = (const float*)d_in[1];
  int* codes = (int*)d_out;

  const size_t R_BYTES   = (size_t)M_TOTAL * DDIM * 4;            // 32 MB f32 residual
  const size_t E16_BYTES = (size_t)NQ * KCODES * DDIM * 2;        // 2 MB f16 codebook
  const size_t EN_BYTES  = (size_t)NQ * KCODES * 4;               // 32 KB
  const size_t need = R_BYTES + E16_BYTES + EN_BYTES + 256;

  if (ws_size >= need) {
    char* w = (char*)d_ws;
    float* resid   = (float*)w;        w += R_BYTES;
    _Float16* Ef16 = (_Float16*)w;     w += E16_BYTES;
    float* enorm   = (float*)w;

    enorm_kernel<<<dim3(NQ * KCODES / 4), dim3(256), 0, stream>>>(embed, enorm);
    esplit16_kernel<<<dim3(NQ * KCODES * DDIM / 8 / 256), dim3(256), 0, stream>>>(embed, Ef16);

    for (int q = 0; q < NQ; ++q) {
      int wr = (q < NQ - 1) ? 1 : 0;
      const float* rin = (q == 0) ? x : resid;
      rvq_stage<<<dim3(M_TOTAL / RROWS), dim3(256), 0, stream>>>(
          rin, resid,
          Ef16 + (size_t)q * KCODES * DDIM,
          embed + (size_t)q * KCODES * DDIM,
          enorm + (size_t)q * KCODES,
          codes + (size_t)q * M_TOTAL, wr);
    }
  } else {
    // fallback: verified round-2 exact-fp32 path
    const size_t resid_elems = (size_t)M_TOTAL * DDIM;
    const bool ws_ok = ws_size >= (resid_elems + (size_t)NQ * KCODES) * sizeof(float);
    float* resid = ws_ok ? (float*)d_ws : (float*)d_in[0];
    float* enorm = ws_ok ? ((float*)d_ws + resid_elems) : (float*)d_ws;

    enorm_kernel<<<dim3(NQ * KCODES / 4), dim3(256), 0, stream>>>(embed, enorm);
    for (int q = 0; q < NQ; ++q) {
      const float* rin = (q == 0) ? x : resid;
      rvq_stage_kernel<<<dim3(M_TOTAL / 64), dim3(256), 0, stream>>>(
          rin, resid, embed + (size_t)q * KCODES * DDIM,
          enorm + (size_t)q * KCODES, codes + (size_t)q * M_TOTAL);
    }
  }
}

// Round 10
// 2328.913 us; speedup vs baseline: 1.2946x; 1.2946x over previous
//
#include <hip/hip_runtime.h>

#define M_TOTAL 65536   // B*T rows
#define DDIM    128     // latent dim (GEMM K)
#define KCODES  1024    // codebook size (GEMM N)
#define NQ      8       // RVQ stages
#define RROWS   64      // rows per block (4 waves in 2x2 row/code grid)
#define NC      64      // codes per Es chunk
#define NCHUNKS (KCODES / NC)
#define TAU     0.15f   // margin threshold (validated rounds 5-9, absmax 0)

typedef _Float16 half8 __attribute__((ext_vector_type(8)));
typedef float    f32x4 __attribute__((ext_vector_type(4)));

// ---------------- ||e||^2 (verified round-1 semantics) ----------------
__global__ __launch_bounds__(256) void enorm_kernel(const float* __restrict__ embed,
                                                    float* __restrict__ enorm) {
  int c = blockIdx.x * 4 + (threadIdx.x >> 6);
  int lane = threadIdx.x & 63;
  const float* e = embed + (size_t)c * DDIM;
  float v0 = e[lane];
  float v1 = e[lane + 64];
  float s = fmaf(v0, v0, v1 * v1);
  #pragma unroll
  for (int off = 32; off > 0; off >>= 1) s += __shfl_down(s, off);
  if (lane == 0) enorm[c] = s;
}

// ---------------- embed -> f16 plane, row-major ----------------
__global__ __launch_bounds__(256) void esplit16_kernel(const float* __restrict__ embed,
                                                       _Float16* __restrict__ Ef16) {
  size_t base = ((size_t)blockIdx.x * 256 + threadIdx.x) * 8;
  float4 v0 = *(const float4*)(embed + base);
  float4 v1 = *(const float4*)(embed + base + 4);
  half8 h;
  h[0] = (_Float16)v0.x; h[1] = (_Float16)v0.y; h[2] = (_Float16)v0.z; h[3] = (_Float16)v0.w;
  h[4] = (_Float16)v1.x; h[5] = (_Float16)v1.y; h[6] = (_Float16)v1.z; h[7] = (_Float16)v1.w;
  *(half8*)(Ef16 + base) = h;
}

// ---------------- one RVQ stage: dbuf f16 MFMA screen + in-block exact fixup ----
// Block: 64 rows x 1024 codes (16 chunks of 64). 4 waves 2x2: rw=wv&1 -> rows
// rw*32 + rt*16 + l15; cw=wv>>1 -> codes cw*32 + ct*16 + l15 within a chunk.
// Es double-buffered (1 barrier/chunk); grid 1024 blocks. LDS 35 KB -> 4
// blocks/CU capacity; __launch_bounds__(256,2) leaves VGPR alloc to demand
// (~110 <= 128) so 4 waves/EU remain schedulable. NOTE: (256,4) forced VGPR=64
// and spilled (round 9: WRITE 343 MB); do not re-tighten.
__global__ __launch_bounds__(256, 2) void rvq_stage(
    const float* __restrict__ rin, float* __restrict__ rout,
    const _Float16* __restrict__ Ef16S,     // [KCODES][DDIM] f16, this stage
    const float* __restrict__ embedS,       // [KCODES][DDIM] fp32, this stage
    const float* __restrict__ enormS,       // [KCODES]
    int* __restrict__ codesS,               // [M_TOTAL] this stage
    int write_resid)
{
  __shared__ _Float16 Es[2][NC * 136];      // 2 x 17408 B
  __shared__ int nflag;
  // overlays on Es after the main loop (Es dead then; barriers order reuse):
  float* redv1  = (float*)Es;               // [64][2]
  float* redv2  = redv1 + 128;              // [64][2]
  int*   redi1  = (int*)(redv2 + 128);      // [64][2]
  int*   bcode  = redi1 + 128;              // [64]
  int*   flagged= bcode + 64;               // [64]
  float* rowbuf = (float*)(flagged + 64);   // [128]
  float* fv     = rowbuf + 128;             // [256]
  int*   fidx   = (int*)(fv + 256);         // [256]

  const int tid = threadIdx.x;
  const int wv = tid >> 6;
  const int l  = tid & 63;
  const int l15 = l & 15;
  const int q = l >> 4;
  const int rw = wv & 1;
  const int cw = wv >> 1;
  const int row_base = blockIdx.x * RROWS;

  if (tid == 0) nflag = 0;

  // staging indices (64 codes x 128 k per chunk; 4 half8 per thread, coalesced)
  const int s_code = tid >> 4;              // 0..15 (+16 per it)
  const int s_kp   = tid & 15;

  // ---- build f16 A-frags from global (once): af[rt][kc], A[m=l15][k=q*8+j] ----
  half8 af[2][4];
  #pragma unroll
  for (int rt = 0; rt < 2; ++rt) {
    const float* pa = rin + (size_t)(row_base + rw * 32 + rt * 16 + l15) * DDIM;
    #pragma unroll
    for (int kc = 0; kc < 4; ++kc) {
      float4 x0 = *(const float4*)(pa + kc * 32 + q * 8);
      float4 x1 = *(const float4*)(pa + kc * 32 + q * 8 + 4);
      half8 h;
      h[0] = (_Float16)x0.x; h[1] = (_Float16)x0.y; h[2] = (_Float16)x0.z; h[3] = (_Float16)x0.w;
      h[4] = (_Float16)x1.x; h[5] = (_Float16)x1.y; h[6] = (_Float16)x1.z; h[7] = (_Float16)x1.w;
      af[rt][kc] = h;
    }
  }

  // ---- prologue: stage chunk 0 into Es[0] ----
  half8 pre[4];
  #pragma unroll
  for (int it = 0; it < 4; ++it)
    pre[it] = *(const half8*)(Ef16S + (size_t)(it * 16 + s_code) * DDIM + s_kp * 8);
  #pragma unroll
  for (int it = 0; it < 4; ++it)
    *(half8*)(&Es[0][(it * 16 + s_code) * 136 + s_kp * 8]) = pre[it];
  __syncthreads();

  float v1[8], v2[8];
  int i1[8];
  #pragma unroll
  for (int s = 0; s < 8; ++s) { v1[s] = -3.0e38f; v2[s] = -3.0e38f; i1[s] = 0x7fffffff; }

  for (int cc = 0; cc < NCHUNKS; ++cc) {
    const int cur = cc & 1;

    // issue global loads for chunk cc+1 (latency hides behind this chunk's compute)
    if (cc + 1 < NCHUNKS) {
      #pragma unroll
      for (int it = 0; it < 4; ++it)
        pre[it] = *(const half8*)(Ef16S + (size_t)((cc + 1) * NC + it * 16 + s_code) * DDIM + s_kp * 8);
    }
    float enr0 = enormS[cc * NC + cw * 32 + l15];
    float enr1 = enormS[cc * NC + cw * 32 + 16 + l15];

    f32x4 acc[2][2];
    #pragma unroll
    for (int rt = 0; rt < 2; ++rt)
      #pragma unroll
      for (int ct = 0; ct < 2; ++ct) acc[rt][ct] = (f32x4){0.f, 0.f, 0.f, 0.f};

    #pragma unroll
    for (int kc = 0; kc < 4; ++kc) {
      half8 bf0 = *(const half8*)(&Es[cur][(cw * 32 + l15) * 136 + kc * 32 + q * 8]);
      half8 bf1 = *(const half8*)(&Es[cur][(cw * 32 + 16 + l15) * 136 + kc * 32 + q * 8]);
      #pragma unroll
      for (int rt = 0; rt < 2; ++rt) {
        acc[rt][0] = __builtin_amdgcn_mfma_f32_16x16x32_f16(af[rt][kc], bf0, acc[rt][0], 0, 0, 0);
        acc[rt][1] = __builtin_amdgcn_mfma_f32_16x16x32_f16(af[rt][kc], bf1, acc[rt][1], 0, 0, 0);
      }
    }

    // epilogue: dist = 2*dot - ||e||^2; branchless top-2 (inline, NO lambda --
    // round-8 lambda caused scratch spill). Codes ascend -> strict > keeps
    // first occurrence; exact ties -> margin 0 <= TAU -> exact fixup decides.
    #pragma unroll
    for (int ct = 0; ct < 2; ++ct) {
      float en = ct ? enr1 : enr0;
      int cgi = cc * NC + cw * 32 + ct * 16 + l15;
      #pragma unroll
      for (int rt = 0; rt < 2; ++rt)
        #pragma unroll
        for (int reg = 0; reg < 4; ++reg) {
          float d = fmaf(2.0f, acc[rt][ct][reg], -en);
          int s = rt * 4 + reg;
          v2[s] = fmaxf(v2[s], fminf(d, v1[s]));
          if (d > v1[s]) i1[s] = cgi;
          v1[s] = fmaxf(v1[s], d);
        }
    }

    // write prefetched chunk into the other buffer; one barrier per chunk
    if (cc + 1 < NCHUNKS) {
      #pragma unroll
      for (int it = 0; it < 4; ++it)
        *(half8*)(&Es[cur ^ 1][(it * 16 + s_code) * 136 + s_kp * 8]) = pre[it];
    }
    __syncthreads();
  }

  // ---- merge top-2 across the 16 l15-lanes sharing each row (disjoint codes) ----
  #pragma unroll
  for (int s = 0; s < 8; ++s) {
    #pragma unroll
    for (int off = 1; off < 16; off <<= 1) {
      float ov1 = __shfl_xor(v1[s], off);
      int   oi1 = __shfl_xor(i1[s], off);
      float ov2 = __shfl_xor(v2[s], off);
      if (ov1 > v1[s] || (ov1 == v1[s] && oi1 < i1[s])) {
        float nv2 = fmaxf(v1[s], ov2);
        v1[s] = ov1; i1[s] = oi1; v2[s] = nv2;
      } else {
        v2[s] = fmaxf(v2[s], ov1);
      }
    }
  }
  if (l15 == 0) {
    #pragma unroll
    for (int s = 0; s < 8; ++s) {
      int row = rw * 32 + (s >> 2) * 16 + q * 4 + (s & 3);
      redv1[row * 2 + cw] = v1[s];
      redi1[row * 2 + cw] = i1[s];
      redv2[row * 2 + cw] = v2[s];
    }
  }
  __syncthreads();

  // ---- final per-row merge (2 code-groups), flag, best code ----
  if (tid < RROWS) {
    float a1 = redv1[tid * 2], a2 = redv2[tid * 2];
    int ai = redi1[tid * 2];
    float b1v = redv1[tid * 2 + 1], b2v = redv2[tid * 2 + 1];
    int bi = redi1[tid * 2 + 1];
    float bv1, bv2; int bidx;
    if (b1v > a1 || (b1v == a1 && bi < ai)) {
      bv1 = b1v; bidx = bi; bv2 = fmaxf(a1, b2v);
    } else {
      bv1 = a1; bidx = ai; bv2 = fmaxf(b1v, a2);
    }
    bcode[tid] = bidx;
    if (bv1 - bv2 <= TAU) {
      int pos = atomicAdd(&nflag, 1);
      flagged[pos] = tid;
    }
  }
  __syncthreads();

  // ---- in-block exact fixup for flagged rows (round-1-verified fp32 semantics;
  //      rin IS the exact f32 residual for this stage) ----
  const int nfl = nflag;
  for (int f = 0; f < nfl; ++f) {
    const int r = flagged[f];
    if (tid < 32)
      *(float4*)(rowbuf + tid * 4) =
          *(const float4*)(rin + (size_t)(row_base + r) * DDIM + tid * 4);
    __syncthreads();

    float acc0 = 0.f, acc1 = 0.f, acc2 = 0.f, acc3 = 0.f;
    for (int k4 = 0; k4 < 32; ++k4) {
      float4 rb = *(const float4*)(&rowbuf[k4 * 4]);
      const float* eb = embedS + (size_t)tid * 4 * DDIM + k4 * 4;
      float4 e0 = *(const float4*)eb;
      float4 e1 = *(const float4*)(eb + DDIM);
      float4 e2 = *(const float4*)(eb + 2 * DDIM);
      float4 e3 = *(const float4*)(eb + 3 * DDIM);
      acc0 = fmaf(rb.x, e0.x, acc0); acc0 = fmaf(rb.y, e0.y, acc0);
      acc0 = fmaf(rb.z, e0.z, acc0); acc0 = fmaf(rb.w, e0.w, acc0);
      acc1 = fmaf(rb.x, e1.x, acc1); acc1 = fmaf(rb.y, e1.y, acc1);
      acc1 = fmaf(rb.z, e1.z, acc1); acc1 = fmaf(rb.w, e1.w, acc1);
      acc2 = fmaf(rb.x, e2.x, acc2); acc2 = fmaf(rb.y, e2.y, acc2);
      acc2 = fmaf(rb.z, e2.z, acc2); acc2 = fmaf(rb.w, e2.w, acc2);
      acc3 = fmaf(rb.x, e3.x, acc3); acc3 = fmaf(rb.y, e3.y, acc3);
      acc3 = fmaf(rb.z, e3.z, acc3); acc3 = fmaf(rb.w, e3.w, acc3);
    }
    float bv = -3.0e38f; int bi = 0x7fffffff;
    {
      float dd0 = 2.0f * acc0 - enormS[tid * 4 + 0];
      float dd1 = 2.0f * acc1 - enormS[tid * 4 + 1];
      float dd2 = 2.0f * acc2 - enormS[tid * 4 + 2];
      float dd3 = 2.0f * acc3 - enormS[tid * 4 + 3];
      bv = dd0; bi = tid * 4 + 0;
      if (dd1 > bv) { bv = dd1; bi = tid * 4 + 1; }
      if (dd2 > bv) { bv = dd2; bi = tid * 4 + 2; }
      if (dd3 > bv) { bv = dd3; bi = tid * 4 + 3; }
    }
    fv[tid] = bv; fidx[tid] = bi;
    __syncthreads();
    for (int step = 128; step > 0; step >>= 1) {
      if (tid < step) {
        float o = fv[tid + step]; int oi = fidx[tid + step];
        if (o > fv[tid] || (o == fv[tid] && oi < fidx[tid])) { fv[tid] = o; fidx[tid] = oi; }
      }
      __syncthreads();
    }
    if (tid == 0) bcode[r] = fidx[0];
    __syncthreads();
  }

  // ---- write codes; exact f32 residual update (block owns its rows) ----
  if (tid < RROWS) codesS[row_base + tid] = bcode[tid];
  __syncthreads();

  if (write_resid) {
    #pragma unroll
    for (int it = 0; it < 8; ++it) {
      int idx = it * 256 + tid;
      int r = idx >> 5, f4 = idx & 31;
      float4 e = *(const float4*)(embedS + (size_t)bcode[r] * DDIM + f4 * 4);
      float4 a = *(const float4*)(rin + (size_t)(row_base + r) * DDIM + f4 * 4);
      float4 o;
      o.x = a.x - e.x; o.y = a.y - e.y; o.z = a.z - e.z; o.w = a.w - e.w;
      *(float4*)(rout + (size_t)(row_base + r) * DDIM + f4 * 4) = o;
    }
  }
}

// ================= fallback: round-2 verified exact-fp32 kernel =================
#define F_NCHUNK  256
#define F_KC      16
#define F_AS_STRIDE 68
#define F_ES_STRIDE 260

__global__ __launch_bounds__(256, 3) void rvq_stage_kernel(
    const float* __restrict__ rin, float* __restrict__ rout,
    const float* __restrict__ embed, const float* __restrict__ enorm,
    int* __restrict__ codes)
{
  __shared__ float smem[DDIM * F_AS_STRIDE + F_KC * F_ES_STRIDE + F_NCHUNK];
  float* As  = smem;
  float* Es  = smem + DDIM * F_AS_STRIDE;
  float* Ens = Es + F_KC * F_ES_STRIDE;
  float* red_v = Es;
  int*   red_i = (int*)(Es + 64 * 33);
  int*   bcode = (int*)(Es + 2 * 64 * 33);

  const int tid = threadIdx.x;
  const int tx = tid & 31;
  const int ty = tid >> 5;
  const int row_base = blockIdx.x * 64;

  #pragma unroll
  for (int it = 0; it < 8; ++it) {
    int idx = it * 256 + tid;
    int r = idx >> 5, f4 = idx & 31;
    float4 v = *(const float4*)(rin + (size_t)(row_base + r) * DDIM + f4 * 4);
    As[(4 * f4 + 0) * F_AS_STRIDE + r] = v.x;
    As[(4 * f4 + 1) * F_AS_STRIDE + r] = v.y;
    As[(4 * f4 + 2) * F_AS_STRIDE + r] = v.z;
    As[(4 * f4 + 3) * F_AS_STRIDE + r] = v.w;
  }

  float best[8]; int bidx[8];
  #pragma unroll
  for (int i = 0; i < 8; ++i) { best[i] = -3.0e38f; bidx[i] = 0x7fffffff; }

  for (int nc = 0; nc < KCODES / F_NCHUNK; ++nc) {
    float acc[8][8];
    #pragma unroll
    for (int i = 0; i < 8; ++i)
      #pragma unroll
      for (int j = 0; j < 8; ++j) acc[i][j] = 0.0f;

    for (int kc = 0; kc < DDIM / F_KC; ++kc) {
      __syncthreads();
      #pragma unroll
      for (int it = 0; it < 4; ++it) {
        int idx = it * 256 + tid;
        int c = idx >> 2, f4 = idx & 3;
        float4 v = *(const float4*)(embed + (size_t)(nc * F_NCHUNK + c) * DDIM + kc * F_KC + f4 * 4);
        Es[(4 * f4 + 0) * F_ES_STRIDE + c] = v.x;
        Es[(4 * f4 + 1) * F_ES_STRIDE + c] = v.y;
        Es[(4 * f4 + 2) * F_ES_STRIDE + c] = v.z;
        Es[(4 * f4 + 3) * F_ES_STRIDE + c] = v.w;
      }
      if (kc == 0) Ens[tid] = enorm[nc * F_NCHUNK + tid];
      __syncthreads();

      const float* pa = As + kc * F_KC * F_AS_STRIDE + ty * 8;
      const float* pe = Es + 4 * tx;
      #pragma unroll 4
      for (int k = 0; k < F_KC; ++k) {
        float4 a0 = *(const float4*)(pa + k * F_AS_STRIDE);
        float4 a1 = *(const float4*)(pa + k * F_AS_STRIDE + 4);
        float4 e0 = *(const float4*)(pe + k * F_ES_STRIDE);
        float4 e1 = *(const float4*)(pe + k * F_ES_STRIDE + 128);
        float aa[8] = {a0.x, a0.y, a0.z, a0.w, a1.x, a1.y, a1.z, a1.w};
        float ee[8] = {e0.x, e0.y, e0.z, e0.w, e1.x, e1.y, e1.z, e1.w};
        #pragma unroll
        for (int i = 0; i < 8; ++i)
          #pragma unroll
          for (int j = 0; j < 8; ++j)
            acc[i][j] = fmaf(aa[i], ee[j], acc[i][j]);
      }
    }

    #pragma unroll
    for (int j = 0; j < 8; ++j) {
      int c_local = (j < 4) ? (4 * tx + j) : (128 + 4 * tx + (j - 4));
      float en = Ens[c_local];
      int cg = nc * F_NCHUNK + c_local;
      #pragma unroll
      for (int i = 0; i < 8; ++i) {
        float dist = 2.0f * acc[i][j] - en;
        if (dist > best[i] || (dist == best[i] && cg < bidx[i])) { best[i] = dist; bidx[i] = cg; }
      }
    }
  }

  __syncthreads();
  #pragma unroll
  for (int i = 0; i < 8; ++i) {
    red_v[(ty * 8 + i) * 33 + tx] = best[i];
    red_i[(ty * 8 + i) * 33 + tx] = bidx[i];
  }
  __syncthreads();
  if (tid < 64) {
    float bv = red_v[tid * 33]; int bi = red_i[tid * 33];
    #pragma unroll
    for (int t = 1; t < 32; ++t) {
      float v = red_v[tid * 33 + t]; int ix = red_i[tid * 33 + t];
      if (v > bv || (v == bv && ix < bi)) { bv = v; bi = ix; }
    }
    codes[row_base + tid] = bi;
    bcode[tid] = bi;
  }
  __syncthreads();
  #pragma unroll
  for (int it = 0; it < 32; ++it) {
    int idx = it * 256 + tid;
    int r = idx >> 7, d = idx & 127;
    float e = embed[(size_t)bcode[r] * DDIM + d];
    rout[(size_t)(row_base + r) * DDIM + d] = As[d * F_AS_STRIDE + r] - e;
  }
}

extern "C" void kernel_launch(void* const* d_in, const int* in_sizes, int n_in,
                              void* d_out, int out_size, void* d_ws, size_t ws_size,
                              hipStream_t stream) {
  (void)in_sizes; (void)n_in; (void)out_size;
  const float* x = (const float*)d_in[0];
  const float* embed = (const float*)d_in[1];
  int* codes = (int*)d_out;

  const size_t R_BYTES   = (size_t)M_TOTAL * DDIM * 4;            // 32 MB f32 residual
  const size_t E16_BYTES = (size_t)NQ * KCODES * DDIM * 2;        // 2 MB f16 codebook
  const size_t EN_BYTES  = (size_t)NQ * KCODES * 4;               // 32 KB
  const size_t need = R_BYTES + E16_BYTES + EN_BYTES + 256;

  if (ws_size >= need) {
    char* w = (char*)d_ws;
    float* resid   = (float*)w;        w += R_BYTES;
    _Float16* Ef16 = (_Float16*)w;     w += E16_BYTES;
    float* enorm   = (float*)w;

    enorm_kernel<<<dim3(NQ * KCODES / 4), dim3(256), 0, stream>>>(embed, enorm);
    esplit16_kernel<<<dim3(NQ * KCODES * DDIM / 8 / 256), dim3(256), 0, stream>>>(embed, Ef16);

    for (int q = 0; q < NQ; ++q) {
      int wr = (q < NQ - 1) ? 1 : 0;
      const float* rin = (q == 0) ? x : resid;
      rvq_stage<<<dim3(M_TOTAL / RROWS), dim3(256), 0, stream>>>(
          rin, resid,
          Ef16 + (size_t)q * KCODES * DDIM,
          embed + (size_t)q * KCODES * DDIM,
          enorm + (size_t)q * KCODES,
          codes + (size_t)q * M_TOTAL, wr);
    }
  } else {
    // fallback: verified round-2 exact-fp32 path
    const size_t resid_elems = (size_t)M_TOTAL * DDIM;
    const bool ws_ok = ws_size >= (resid_elems + (size_t)NQ * KCODES) * sizeof(float);
    float* resid = ws_ok ? (float*)d_ws : (float*)d_in[0];
    float* enorm = ws_ok ? ((float*)d_ws + resid_elems) : (float*)d_ws;

    enorm_kernel<<<dim3(NQ * KCODES / 4), dim3(256), 0, stream>>>(embed, enorm);
    for (int q = 0; q < NQ; ++q) {
      const float* rin = (q == 0) ? x : resid;
      rvq_stage_kernel<<<dim3(M_TOTAL / 64), dim3(256), 0, stream>>>(
          rin, resid, embed + (size_t)q * KCODES * DDIM,
          enorm + (size_t)q * KCODES, codes + (size_t)q * M_TOTAL);
    }
  }
}

// Round 11
// 715.119 us; speedup vs baseline: 4.2160x; 3.2567x over previous
//
#include <hip/hip_runtime.h>

#define M_TOTAL 65536   // B*T rows
#define DDIM    128     // latent dim (GEMM K)
#define KCODES  1024    // codebook size (GEMM N)
#define NQ      8       // RVQ stages
#define RROWS   64      // rows per block (4 waves, 2x2 row/code grid) -> 1024 blocks
#define NC      64      // codes per Es chunk
#define NCHUNKS (KCODES / NC)
#define TAU     0.15f   // margin threshold (validated rounds 5-10, absmax 0)
#define FB      8       // fixup rows per batch
#define FIXGRID 256

typedef _Float16 half8 __attribute__((ext_vector_type(8)));
typedef float    f32x4 __attribute__((ext_vector_type(4)));

// ---------------- ||e||^2 (verified round-1 semantics) + nfp zeroing ----------------
__global__ __launch_bounds__(256) void enorm_kernel(const float* __restrict__ embed,
                                                    float* __restrict__ enorm,
                                                    int* __restrict__ nfp) {
  if (blockIdx.x == 0 && threadIdx.x < NQ) nfp[threadIdx.x] = 0;
  int c = blockIdx.x * 4 + (threadIdx.x >> 6);
  int lane = threadIdx.x & 63;
  const float* e = embed + (size_t)c * DDIM;
  float v0 = e[lane];
  float v1 = e[lane + 64];
  float s = fmaf(v0, v0, v1 * v1);
  #pragma unroll
  for (int off = 32; off > 0; off >>= 1) s += __shfl_down(s, off);
  if (lane == 0) enorm[c] = s;
}

// ---------------- embed -> f16 plane, row-major ----------------
__global__ __launch_bounds__(256) void esplit16_kernel(const float* __restrict__ embed,
                                                       _Float16* __restrict__ Ef16) {
  size_t base = ((size_t)blockIdx.x * 256 + threadIdx.x) * 8;
  float4 v0 = *(const float4*)(embed + base);
  float4 v1 = *(const float4*)(embed + base + 4);
  half8 h;
  h[0] = (_Float16)v0.x; h[1] = (_Float16)v0.y; h[2] = (_Float16)v0.z; h[3] = (_Float16)v0.w;
  h[4] = (_Float16)v1.x; h[5] = (_Float16)v1.y; h[6] = (_Float16)v1.z; h[7] = (_Float16)v1.w;
  *(half8*)(Ef16 + base) = h;
}

// ---------------- screen: dbuf f16 MFMA + top-2 margin -> global flag list ----------
// Block: 64 rows x 1024 codes (16 chunks of 64). 4 waves 2x2: rw=wv&1 -> rows
// rw*32 + rt*16 + l15; cw=wv>>1 -> codes cw*32 + ct*16 + l15 within a chunk.
// Es double-buffered (1 barrier/chunk). Grid 1024 blocks -> 4 blocks/CU (LDS
// 36 KB x 4 = 145 KB <= 160 KB). Fixup is a SEPARATE kernel: merging it into
// this kernel caused scratch spill in rounds 8-10 (WRITE_SIZE 160-340 MB).
__global__ __launch_bounds__(256, 2) void rvq_screen(
    const float* __restrict__ rin, float* __restrict__ rout,
    const _Float16* __restrict__ Ef16S,     // [KCODES][DDIM] f16, this stage
    const float* __restrict__ embedS,       // [KCODES][DDIM] fp32, this stage
    const float* __restrict__ enormS,       // [KCODES]
    int* __restrict__ codesS,               // [M_TOTAL] this stage
    int* __restrict__ flistS, int* __restrict__ nfpS,
    int write_resid)
{
  __shared__ _Float16 Es[2][NC * 136];      // 2 x 17408 B
  __shared__ float redv1[RROWS * 2];
  __shared__ float redv2[RROWS * 2];
  __shared__ int   redi1[RROWS * 2];
  __shared__ int   bcode[RROWS];

  const int tid = threadIdx.x;
  const int wv = tid >> 6;
  const int l  = tid & 63;
  const int l15 = l & 15;
  const int q = l >> 4;
  const int rw = wv & 1;
  const int cw = wv >> 1;
  const int row_base = blockIdx.x * RROWS;

  // staging indices (64 codes x 128 k per chunk; 4 half8 per thread, coalesced)
  const int s_code = tid >> 4;              // 0..15 (+16 per it)
  const int s_kp   = tid & 15;

  // ---- build f16 A-frags from global (once): af[rt][kc], A[m=l15][k=q*8+j] ----
  half8 af[2][4];
  #pragma unroll
  for (int rt = 0; rt < 2; ++rt) {
    const float* pa = rin + (size_t)(row_base + rw * 32 + rt * 16 + l15) * DDIM;
    #pragma unroll
    for (int kc = 0; kc < 4; ++kc) {
      float4 x0 = *(const float4*)(pa + kc * 32 + q * 8);
      float4 x1 = *(const float4*)(pa + kc * 32 + q * 8 + 4);
      half8 h;
      h[0] = (_Float16)x0.x; h[1] = (_Float16)x0.y; h[2] = (_Float16)x0.z; h[3] = (_Float16)x0.w;
      h[4] = (_Float16)x1.x; h[5] = (_Float16)x1.y; h[6] = (_Float16)x1.z; h[7] = (_Float16)x1.w;
      af[rt][kc] = h;
    }
  }

  // ---- prologue: stage chunk 0 into Es[0] ----
  half8 pre[4];
  #pragma unroll
  for (int it = 0; it < 4; ++it)
    pre[it] = *(const half8*)(Ef16S + (size_t)(it * 16 + s_code) * DDIM + s_kp * 8);
  #pragma unroll
  for (int it = 0; it < 4; ++it)
    *(half8*)(&Es[0][(it * 16 + s_code) * 136 + s_kp * 8]) = pre[it];
  __syncthreads();

  float v1[8], v2[8];
  int i1[8];
  #pragma unroll
  for (int s = 0; s < 8; ++s) { v1[s] = -3.0e38f; v2[s] = -3.0e38f; i1[s] = 0x7fffffff; }

  for (int cc = 0; cc < NCHUNKS; ++cc) {
    const int cur = cc & 1;

    // issue global loads for chunk cc+1 (latency hides behind this chunk's compute)
    if (cc + 1 < NCHUNKS) {
      #pragma unroll
      for (int it = 0; it < 4; ++it)
        pre[it] = *(const half8*)(Ef16S + (size_t)((cc + 1) * NC + it * 16 + s_code) * DDIM + s_kp * 8);
    }
    float enr0 = enormS[cc * NC + cw * 32 + l15];
    float enr1 = enormS[cc * NC + cw * 32 + 16 + l15];

    f32x4 acc[2][2];
    #pragma unroll
    for (int rt = 0; rt < 2; ++rt)
      #pragma unroll
      for (int ct = 0; ct < 2; ++ct) acc[rt][ct] = (f32x4){0.f, 0.f, 0.f, 0.f};

    #pragma unroll
    for (int kc = 0; kc < 4; ++kc) {
      half8 bf0 = *(const half8*)(&Es[cur][(cw * 32 + l15) * 136 + kc * 32 + q * 8]);
      half8 bf1 = *(const half8*)(&Es[cur][(cw * 32 + 16 + l15) * 136 + kc * 32 + q * 8]);
      #pragma unroll
      for (int rt = 0; rt < 2; ++rt) {
        acc[rt][0] = __builtin_amdgcn_mfma_f32_16x16x32_f16(af[rt][kc], bf0, acc[rt][0], 0, 0, 0);
        acc[rt][1] = __builtin_amdgcn_mfma_f32_16x16x32_f16(af[rt][kc], bf1, acc[rt][1], 0, 0, 0);
      }
    }

    // epilogue: dist = 2*dot - ||e||^2; branchless top-2 (inline, no lambda).
    // Codes ascend -> strict > keeps first occurrence; exact ties -> margin 0
    // <= TAU -> exact fixup decides.
    #pragma unroll
    for (int ct = 0; ct < 2; ++ct) {
      float en = ct ? enr1 : enr0;
      int cgi = cc * NC + cw * 32 + ct * 16 + l15;
      #pragma unroll
      for (int rt = 0; rt < 2; ++rt)
        #pragma unroll
        for (int reg = 0; reg < 4; ++reg) {
          float d = fmaf(2.0f, acc[rt][ct][reg], -en);
          int s = rt * 4 + reg;
          v2[s] = fmaxf(v2[s], fminf(d, v1[s]));
          if (d > v1[s]) i1[s] = cgi;
          v1[s] = fmaxf(v1[s], d);
        }
    }

    // write prefetched chunk into the other buffer; one barrier per chunk
    if (cc + 1 < NCHUNKS) {
      #pragma unroll
      for (int it = 0; it < 4; ++it)
        *(half8*)(&Es[cur ^ 1][(it * 16 + s_code) * 136 + s_kp * 8]) = pre[it];
    }
    __syncthreads();
  }

  // ---- merge top-2 across the 16 l15-lanes sharing each row (disjoint codes) ----
  #pragma unroll
  for (int s = 0; s < 8; ++s) {
    #pragma unroll
    for (int off = 1; off < 16; off <<= 1) {
      float ov1 = __shfl_xor(v1[s], off);
      int   oi1 = __shfl_xor(i1[s], off);
      float ov2 = __shfl_xor(v2[s], off);
      if (ov1 > v1[s] || (ov1 == v1[s] && oi1 < i1[s])) {
        float nv2 = fmaxf(v1[s], ov2);
        v1[s] = ov1; i1[s] = oi1; v2[s] = nv2;
      } else {
        v2[s] = fmaxf(v2[s], ov1);
      }
    }
  }
  if (l15 == 0) {
    #pragma unroll
    for (int s = 0; s < 8; ++s) {
      int row = rw * 32 + (s >> 2) * 16 + q * 4 + (s & 3);
      redv1[row * 2 + cw] = v1[s];
      redi1[row * 2 + cw] = i1[s];
      redv2[row * 2 + cw] = v2[s];
    }
  }
  __syncthreads();

  // ---- final per-row merge (2 code-groups), flag to GLOBAL list, best code ----
  if (tid < RROWS) {
    float a1 = redv1[tid * 2], a2 = redv2[tid * 2];
    int ai = redi1[tid * 2];
    float b1v = redv1[tid * 2 + 1], b2v = redv2[tid * 2 + 1];
    int bi = redi1[tid * 2 + 1];
    float bv1, bv2; int bidx;
    if (b1v > a1 || (b1v == a1 && bi < ai)) {
      bv1 = b1v; bidx = bi; bv2 = fmaxf(a1, b2v);
    } else {
      bv1 = a1; bidx = ai; bv2 = fmaxf(b1v, a2);
    }
    bcode[tid] = bidx;
    codesS[row_base + tid] = bidx;
    if (bv1 - bv2 <= TAU) {
      int pos = atomicAdd(nfpS, 1);
      flistS[pos] = row_base + tid;
    }
  }
  __syncthreads();

  // ---- exact f32 residual update: rout = rin - embed[code] (block owns rows) ----
  if (write_resid) {
    #pragma unroll
    for (int it = 0; it < 8; ++it) {
      int idx = it * 256 + tid;
      int r = idx >> 5, f4 = idx & 31;
      float4 e = *(const float4*)(embedS + (size_t)bcode[r] * DDIM + f4 * 4);
      float4 a = *(const float4*)(rin + (size_t)(row_base + r) * DDIM + f4 * 4);
      float4 o;
      o.x = a.x - e.x; o.y = a.y - e.y; o.z = a.z - e.z; o.w = a.w - e.w;
      *(float4*)(rout + (size_t)(row_base + r) * DDIM + f4 * 4) = o;
    }
  }
}

// ---------------- batched exact fixup (round-1-verified fp32 semantics) ----------------
// Wave-shuffle argmax reduction (1 barrier/row instead of 8-step tree).
__global__ __launch_bounds__(256) void rvq_fixup(
    const float* __restrict__ x,
    const float* __restrict__ embed_all, const float* __restrict__ enorm_all,
    int* __restrict__ codes, float* __restrict__ resid,
    const int* __restrict__ flistS, const int* __restrict__ nfpS,
    int stage, int write_resid)
{
  __shared__ float rowbuf[FB][DDIM];
  __shared__ float wv_v[4];
  __shared__ int   wv_i[4];
  __shared__ int rowid[FB];
  __shared__ int bestc[FB];
  const int tid = threadIdx.x;
  const int lane = tid & 63;
  const int wv = tid >> 6;
  const int n = *nfpS;
  const float* embedS = embed_all + (size_t)stage * KCODES * DDIM;
  const float* enormS = enorm_all + (size_t)stage * KCODES;

  for (int base = blockIdx.x * FB; base < n; base += FIXGRID * FB) {
    const int nb = min(FB, n - base);
    if (tid < nb) rowid[tid] = flistS[base + tid];
    __syncthreads();

    // reconstruct exact residual: v = x - sum_{s2<stage} embed[codes[s2]] (stage order)
    for (int j0 = 0; j0 < nb; j0 += 2) {
      int j = j0 + (tid >> 7);
      int d = tid & 127;
      if (j < nb) {
        int r = rowid[j];
        float v = x[(size_t)r * DDIM + d];
        for (int s2 = 0; s2 < stage; ++s2) {
          int pc = codes[(size_t)s2 * M_TOTAL + r];
          v -= embed_all[(size_t)(s2 * KCODES + pc) * DDIM + d];
        }
        rowbuf[j][d] = v;
      }
    }
    __syncthreads();

    // exact dots: thread t -> codes {4t..4t+3} x FB rows, sequential-k fmaf chains
    float acc[4][FB];
    #pragma unroll
    for (int jc = 0; jc < 4; ++jc)
      #pragma unroll
      for (int j = 0; j < FB; ++j) acc[jc][j] = 0.f;
    for (int k4 = 0; k4 < 32; ++k4) {
      float4 rb[FB];
      #pragma unroll
      for (int j = 0; j < FB; ++j) rb[j] = *(const float4*)(&rowbuf[j][k4 * 4]);
      #pragma unroll
      for (int jc = 0; jc < 4; ++jc) {
        float4 e4 = *(const float4*)(embedS + (size_t)(tid * 4 + jc) * DDIM + k4 * 4);
        #pragma unroll
        for (int j = 0; j < FB; ++j) {
          acc[jc][j] = fmaf(rb[j].x, e4.x, acc[jc][j]);
          acc[jc][j] = fmaf(rb[j].y, e4.y, acc[jc][j]);
          acc[jc][j] = fmaf(rb[j].z, e4.z, acc[jc][j]);
          acc[jc][j] = fmaf(rb[j].w, e4.w, acc[jc][j]);
        }
      }
    }

    for (int j = 0; j < nb; ++j) {
      float bv = -3.0e38f; int bi = 0x7fffffff;
      #pragma unroll
      for (int jc = 0; jc < 4; ++jc) {
        int c = tid * 4 + jc;
        float dd = 2.0f * acc[jc][j] - enormS[c];
        if (dd > bv) { bv = dd; bi = c; }   // jc ascending -> first occurrence
      }
      // wave-level argmax (lowest-index tie-break; lane order irrelevant to predicate)
      #pragma unroll
      for (int off = 32; off > 0; off >>= 1) {
        float o = __shfl_down(bv, off);
        int oi = __shfl_down(bi, off);
        if (o > bv || (o == bv && oi < bi)) { bv = o; bi = oi; }
      }
      if (lane == 0) { wv_v[wv] = bv; wv_i[wv] = bi; }
      __syncthreads();
      if (tid == 0) {
        float fbv = wv_v[0]; int fbi = wv_i[0];
        #pragma unroll
        for (int w = 1; w < 4; ++w) {
          float o = wv_v[w]; int oi = wv_i[w];
          if (o > fbv || (o == fbv && oi < fbi)) { fbv = o; fbi = oi; }
        }
        bestc[j] = fbi;
        codes[(size_t)stage * M_TOTAL + rowid[j]] = fbi;
      }
      __syncthreads();
    }

    // rewrite exact f32 residual for flagged rows
    if (write_resid) {
      for (int j0 = 0; j0 < nb; j0 += 2) {
        int j = j0 + (tid >> 7);
        int d = tid & 127;
        if (j < nb) {
          int r = rowid[j];
          resid[(size_t)r * DDIM + d] = rowbuf[j][d] - embedS[(size_t)bestc[j] * DDIM + d];
        }
      }
    }
    __syncthreads();
  }
}

// ================= fallback: round-2 verified exact-fp32 kernel =================
#define F_NCHUNK  256
#define F_KC      16
#define F_AS_STRIDE 68
#define F_ES_STRIDE 260

__global__ __launch_bounds__(256, 3) void rvq_stage_kernel(
    const float* __restrict__ rin, float* __restrict__ rout,
    const float* __restrict__ embed, const float* __restrict__ enorm,
    int* __restrict__ codes)
{
  __shared__ float smem[DDIM * F_AS_STRIDE + F_KC * F_ES_STRIDE + F_NCHUNK];
  float* As  = smem;
  float* Es  = smem + DDIM * F_AS_STRIDE;
  float* Ens = Es + F_KC * F_ES_STRIDE;
  float* red_v = Es;
  int*   red_i = (int*)(Es + 64 * 33);
  int*   bcode = (int*)(Es + 2 * 64 * 33);

  const int tid = threadIdx.x;
  const int tx = tid & 31;
  const int ty = tid >> 5;
  const int row_base = blockIdx.x * 64;

  #pragma unroll
  for (int it = 0; it < 8; ++it) {
    int idx = it * 256 + tid;
    int r = idx >> 5, f4 = idx & 31;
    float4 v = *(const float4*)(rin + (size_t)(row_base + r) * DDIM + f4 * 4);
    As[(4 * f4 + 0) * F_AS_STRIDE + r] = v.x;
    As[(4 * f4 + 1) * F_AS_STRIDE + r] = v.y;
    As[(4 * f4 + 2) * F_AS_STRIDE + r] = v.z;
    As[(4 * f4 + 3) * F_AS_STRIDE + r] = v.w;
  }

  float best[8]; int bidx[8];
  #pragma unroll
  for (int i = 0; i < 8; ++i) { best[i] = -3.0e38f; bidx[i] = 0x7fffffff; }

  for (int nc = 0; nc < KCODES / F_NCHUNK; ++nc) {
    float acc[8][8];
    #pragma unroll
    for (int i = 0; i < 8; ++i)
      #pragma unroll
      for (int j = 0; j < 8; ++j) acc[i][j] = 0.0f;

    for (int kc = 0; kc < DDIM / F_KC; ++kc) {
      __syncthreads();
      #pragma unroll
      for (int it = 0; it < 4; ++it) {
        int idx = it * 256 + tid;
        int c = idx >> 2, f4 = idx & 3;
        float4 v = *(const float4*)(embed + (size_t)(nc * F_NCHUNK + c) * DDIM + kc * F_KC + f4 * 4);
        Es[(4 * f4 + 0) * F_ES_STRIDE + c] = v.x;
        Es[(4 * f4 + 1) * F_ES_STRIDE + c] = v.y;
        Es[(4 * f4 + 2) * F_ES_STRIDE + c] = v.z;
        Es[(4 * f4 + 3) * F_ES_STRIDE + c] = v.w;
      }
      if (kc == 0) Ens[tid] = enorm[nc * F_NCHUNK + tid];
      __syncthreads();

      const float* pa = As + kc * F_KC * F_AS_STRIDE + ty * 8;
      const float* pe = Es + 4 * tx;
      #pragma unroll 4
      for (int k = 0; k < F_KC; ++k) {
        float4 a0 = *(const float4*)(pa + k * F_AS_STRIDE);
        float4 a1 = *(const float4*)(pa + k * F_AS_STRIDE + 4);
        float4 e0 = *(const float4*)(pe + k * F_ES_STRIDE);
        float4 e1 = *(const float4*)(pe + k * F_ES_STRIDE + 128);
        float aa[8] = {a0.x, a0.y, a0.z, a0.w, a1.x, a1.y, a1.z, a1.w};
        float ee[8] = {e0.x, e0.y, e0.z, e0.w, e1.x, e1.y, e1.z, e1.w};
        #pragma unroll
        for (int i = 0; i < 8; ++i)
          #pragma unroll
          for (int j = 0; j < 8; ++j)
            acc[i][j] = fmaf(aa[i], ee[j], acc[i][j]);
      }
    }

    #pragma unroll
    for (int j = 0; j < 8; ++j) {
      int c_local = (j < 4) ? (4 * tx + j) : (128 + 4 * tx + (j - 4));
      float en = Ens[c_local];
      int cg = nc * F_NCHUNK + c_local;
      #pragma unroll
      for (int i = 0; i < 8; ++i) {
        float dist = 2.0f * acc[i][j] - en;
        if (dist > best[i] || (dist == best[i] && cg < bidx[i])) { best[i] = dist; bidx[i] = cg; }
      }
    }
  }

  __syncthreads();
  #pragma unroll
  for (int i = 0; i < 8; ++i) {
    red_v[(ty * 8 + i) * 33 + tx] = best[i];
    red_i[(ty * 8 + i) * 33 + tx] = bidx[i];
  }
  __syncthreads();
  if (tid < 64) {
    float bv = red_v[tid * 33]; int bi = red_i[tid * 33];
    #pragma unroll
    for (int t = 1; t < 32; ++t) {
      float v = red_v[tid * 33 + t]; int ix = red_i[tid * 33 + t];
      if (v > bv || (v == bv && ix < bi)) { bv = v; bi = ix; }
    }
    codes[row_base + tid] = bi;
    bcode[tid] = bi;
  }
  __syncthreads();
  #pragma unroll
  for (int it = 0; it < 32; ++it) {
    int idx = it * 256 + tid;
    int r = idx >> 7, d = idx & 127;
    float e = embed[(size_t)bcode[r] * DDIM + d];
    rout[(size_t)(row_base + r) * DDIM + d] = As[d * F_AS_STRIDE + r] - e;
  }
}

extern "C" void kernel_launch(void* const* d_in, const int* in_sizes, int n_in,
                              void* d_out, int out_size, void* d_ws, size_t ws_size,
                              hipStream_t stream) {
  (void)in_sizes; (void)n_in; (void)out_size;
  const float* x = (const float*)d_in[0];
  const float* embed = (const float*)d_in[1];
  int* codes = (int*)d_out;

  const size_t R_BYTES   = (size_t)M_TOTAL * DDIM * 4;            // 32 MB f32 residual
  const size_t E16_BYTES = (size_t)NQ * KCODES * DDIM * 2;        // 2 MB f16 codebook
  const size_t EN_BYTES  = (size_t)NQ * KCODES * 4;               // 32 KB
  const size_t FL_BYTES  = (size_t)NQ * M_TOTAL * 4;              // 2 MB flag lists
  const size_t need = R_BYTES + E16_BYTES + EN_BYTES + FL_BYTES + 256;

  if (ws_size >= need) {
    char* w = (char*)d_ws;
    float* resid   = (float*)w;        w += R_BYTES;
    _Float16* Ef16 = (_Float16*)w;     w += E16_BYTES;
    float* enorm   = (float*)w;        w += EN_BYTES;
    int* flist     = (int*)w;          w += FL_BYTES;
    int* nfp       = (int*)w;

    enorm_kernel<<<dim3(NQ * KCODES / 4), dim3(256), 0, stream>>>(embed, enorm, nfp);
    esplit16_kernel<<<dim3(NQ * KCODES * DDIM / 8 / 256), dim3(256), 0, stream>>>(embed, Ef16);

    for (int q = 0; q < NQ; ++q) {
      int wr = (q < NQ - 1) ? 1 : 0;
      const float* rin = (q == 0) ? x : resid;
      rvq_screen<<<dim3(M_TOTAL / RROWS), dim3(256), 0, stream>>>(
          rin, resid,
          Ef16 + (size_t)q * KCODES * DDIM,
          embed + (size_t)q * KCODES * DDIM,
          enorm + (size_t)q * KCODES,
          codes + (size_t)q * M_TOTAL,
          flist + (size_t)q * M_TOTAL, nfp + q, wr);
      rvq_fixup<<<dim3(FIXGRID), dim3(256), 0, stream>>>(
          x, embed, enorm, codes, resid,
          flist + (size_t)q * M_TOTAL, nfp + q, q, wr);
    }
  } else {
    // fallback: verified round-2 exact-fp32 path
    const size_t resid_elems = (size_t)M_TOTAL * DDIM;
    const bool ws_ok = ws_size >= (resid_elems + (size_t)NQ * KCODES) * sizeof(float);
    float* resid = ws_ok ? (float*)d_ws : (float*)d_in[0];
    float* enorm = ws_ok ? ((float*)d_ws + resid_elems) : (float*)d_ws;

    enorm_kernel<<<dim3(NQ * KCODES / 4), dim3(256), 0, stream>>>(embed, enorm, (int*)d_ws);
    for (int q = 0; q < NQ; ++q) {
      const float* rin = (q == 0) ? x : resid;
      rvq_stage_kernel<<<dim3(M_TOTAL / 64), dim3(256), 0, stream>>>(
          rin, resid, embed + (size_t)q * KCODES * DDIM,
          enorm + (size_t)q * KCODES, codes + (size_t)q * M_TOTAL);
    }
  }
}